// Round 11
// baseline (3815.239 us; speedup 1.0000x reference)
//
#include <hip/hip_runtime.h>

// Round 19: 2-lanes-per-unit rec, 4-wave blocks, 1 wave/SIMD.
//  - Model from R10-R18 counters: >4-wave blocks stack 2 waves/SIMD
//    (per-step = 2x issue) AND trigger the allocator to park weight arrays
//    in AGPRs (VGPR_Count 60-72 every round). Grid=256=1 block/CU, so the
//    parking bought nothing.
//  - 2 lanes/unit: 200 lanes for l0 -> 4 waves, one per SIMD. Each lane
//    keeps FOUR gate accumulators over its half-slice (R11's bug was two);
//    one dpp_add<0xB1> completes all 4 gate sums in both lanes; one
//    dpp_mov<0xB1> swap exchanges activations. Weights 4 x S f16 =
//    ~100 packed regs/lane -- fits the 256-reg budget at waves_per_eu(1,1).
//  - fdot2/f16 precision path measured in R15/R18: absmax 2.4e-4.
//  - GEMM + serial TC=128 chunk schedule verbatim from baseline.

#define BATCH 256
#define TFULL 1024
#define TC    128
#define NCHUNK (TFULL / TC)

typedef __attribute__((ext_vector_type(2))) _Float16 f16x2;
typedef __attribute__((ext_vector_type(4))) _Float16 f16x4;

__device__ __forceinline__ float fast_rcp(float x) {
    return __builtin_amdgcn_rcpf(x);
}

__device__ __forceinline__ float tanh_fast(float x) {
    float e = __expf(-2.0f * fabsf(x));
    float r = fast_rcp(1.0f + e);
    return copysignf(fmaf(2.0f, r, -1.0f), x);
}

__device__ __forceinline__ float fdot2_(f16x2 a, f16x2 b, float c) {
#if __has_builtin(__builtin_amdgcn_fdot2)
    return __builtin_amdgcn_fdot2(a, b, c, false);
#else
    float d;
    asm("v_dot2_f32_f16 %0, %1, %2, %3" : "=v"(d) : "v"(a), "v"(b), "v"(c));
    return d;
#endif
}

// LDS-only barrier: does NOT drain vmcnt (global loads/stores stay in
// flight). Safe: the rec loop's barrier only orders the LDS h handoff.
__device__ __forceinline__ void lds_barrier() {
    asm volatile("s_waitcnt lgkmcnt(0)\n\ts_barrier" ::: "memory");
}

template<int CTRL>
__device__ __forceinline__ float dpp_add(float v) {
    int t = __builtin_amdgcn_update_dpp(0, __float_as_int(v), CTRL, 0xF, 0xF, true);
    return v + __int_as_float(t);
}
template<int CTRL>
__device__ __forceinline__ float dpp_mov(float v) {
    int t = __builtin_amdgcn_update_dpp(0, __float_as_int(v), CTRL, 0xF, 0xF, true);
    return __int_as_float(t);
}

// ---------------- Phase A: xg = x @ Wx + bias (baseline, verbatim) --------
template<int K, int N>
__global__ __launch_bounds__(256, 2)
void xg_gemm(const float* __restrict__ x, int batchStride,
             const float* __restrict__ Wx,    // [K, N]
             const float* __restrict__ bias,  // [N]
             float* __restrict__ out)
{
    constexpr int K4   = (K + 3) / 4;
    constexpr int SLAB = 64 * 4 + 4;

    const int n0   = blockIdx.x * 64;
    const int row0 = blockIdx.y * 64;
    const int tid  = threadIdx.x;
    const int tx   = tid & 15;
    const int ty   = tid >> 4;

    __shared__ __align__(16) float s_A[K4 * SLAB];
    __shared__ __align__(16) float s_B[K4 * 4 * 64];

    if constexpr ((K % 4) == 0) {
        for (int i = tid; i < 64 * (K / 4); i += 256) {
            const int row = i / (K / 4);
            const int k4  = i % (K / 4);
            const int gr  = row0 + row;
            const int b   = gr >> 7;
            const int t   = gr & 127;
            float4 v = *(const float4*)(x + (size_t)b * batchStride + t * K + k4 * 4);
            *(float4*)(s_A + k4 * SLAB + row * 4) = v;
        }
    } else {
        for (int i = tid; i < 64 * K; i += 256) {
            const int row = i / K;
            const int k   = i % K;
            const int gr  = row0 + row;
            const int b   = gr >> 7;
            const int t   = gr & 127;
            s_A[(k >> 2) * SLAB + row * 4 + (k & 3)] =
                x[(size_t)b * batchStride + t * K + k];
        }
        constexpr int PAD = K4 * 4 - K;
        for (int i = tid; i < 64 * PAD; i += 256) {
            const int row = i / PAD;
            const int kk  = K + i % PAD;
            s_A[(kk >> 2) * SLAB + row * 4 + (kk & 3)] = 0.0f;
        }
    }

    for (int i = tid; i < K4 * 4 * 16; i += 256) {
        const int k  = i >> 4;
        const int c4 = i & 15;
        float4 v = {0.0f, 0.0f, 0.0f, 0.0f};
        if (k < K && n0 + c4 * 4 < N)
            v = *(const float4*)(Wx + (size_t)k * N + n0 + c4 * 4);
        *(float4*)(s_B + k * 64 + c4 * 4) = v;
    }
    __syncthreads();

    float acc[4][4];
#pragma unroll
    for (int r = 0; r < 4; ++r)
#pragma unroll
        for (int c = 0; c < 4; ++c) acc[r][c] = 0.0f;

    for (int k4 = 0; k4 < K4; ++k4) {
        float4 bv[4];
#pragma unroll
        for (int j = 0; j < 4; ++j)
            bv[j] = *(const float4*)(s_B + (k4 * 4 + j) * 64 + tx * 4);
#pragma unroll
        for (int r = 0; r < 4; ++r) {
            float4 av = *(const float4*)(s_A + k4 * SLAB + (ty + 16 * r) * 4);
#pragma unroll
            for (int c = 0; c < 4; ++c) {
                acc[r][c] = fmaf(av.x, ((const float*)&bv[0])[c], acc[r][c]);
                acc[r][c] = fmaf(av.y, ((const float*)&bv[1])[c], acc[r][c]);
                acc[r][c] = fmaf(av.z, ((const float*)&bv[2])[c], acc[r][c]);
                acc[r][c] = fmaf(av.w, ((const float*)&bv[3])[c], acc[r][c]);
            }
        }
    }

    if (n0 + tx * 4 < N) {
        float4 bb = *(const float4*)(bias + n0 + tx * 4);
#pragma unroll
        for (int r = 0; r < 4; ++r) {
            float4 o;
            o.x = acc[r][0] + bb.x;
            o.y = acc[r][1] + bb.y;
            o.z = acc[r][2] + bb.z;
            o.w = acc[r][3] + bb.w;
            *(float4*)(out + (size_t)(row0 + ty + 16 * r) * N + n0 + tx * 4) = o;
        }
    }
}

// ---------------- Phase B: recurrence, 2 lanes/unit ----------------------
// Lane pair (s=0,1) per unit u (lanes 2u, 2u+1). Lane s owns k-slice
// [s*S, s*S+S) and keeps FOUR gate accumulators over it. One
// dpp_add<0xB1> per gate completes the full sum in both lanes. Lane s
// finalizes gates {s, s+2} (lane0: i,cbar; lane1: f,o); one dpp_mov<0xB1>
// swap exchanges activations; c/h update replicated.
template<int U, int S, int BLOCK, bool LAST>
__device__ __forceinline__ void rec2_body(
    _Float16* __restrict__ s_h,     // [2][2*S] f16 in LDS
    const float* __restrict__ xg,   // [B, TC, G]
    const float* __restrict__ Wh,   // [U, G]
    float* __restrict__ xout,       // [B, TC, U] (unless LAST)
    float* __restrict__ c_state,    // [B*U]
    float* __restrict__ h_state,    // [B*U]
    int first,
    const float* __restrict__ Wout, // [U] (LAST)
    const float* __restrict__ bout, // [1] (LAST)
    float* __restrict__ dout)       // [B] (LAST)
{
    constexpr int G  = 4 * U;
    constexpr int HS = 2 * S;

    const int b   = blockIdx.x;
    const int tid = threadIdx.x;
    const int u   = tid >> 1;
    const int s   = tid & 1;
    const bool act_th = (u < U);
    const int uu  = act_th ? u : 0;

    // packed f16 weight pairs, ALL 4 gates over this lane's k-slice:
    // w[g][p] = (Wh[k0][g*U+u], Wh[k0+1][g*U+u]), k0 = s*S + 2p
    f16x2 w[4][S / 2];
#pragma unroll
    for (int g = 0; g < 4; ++g)
#pragma unroll
        for (int p = 0; p < S / 2; ++p) {
            const int k0 = s * S + 2 * p;
            const int k1 = k0 + 1;
            const float wa = (act_th && k0 < U) ? Wh[(size_t)k0 * G + g * U + uu] : 0.0f;
            const float wb = (act_th && k1 < U) ? Wh[(size_t)k1 * G + g * U + uu] : 0.0f;
            w[g][p] = (f16x2){(_Float16)wa, (_Float16)wb};
        }

    for (int i = tid; i < 2 * HS; i += BLOCK) s_h[i] = (_Float16)0.0f;
    __syncthreads();
    if (tid < U) s_h[tid] = (_Float16)(first ? 0.0f : h_state[b * U + tid]);
    float c = first ? 0.0f : c_state[b * U + uu];
    __syncthreads();

    // lane handles gates s (A) and s+2 (B)
    const float* xgpA = xg + (size_t)b * TC * G + (s * U + uu);
    const float* xgpB = xgpA + 2 * U;
    float xA0 = xgpA[0], xA1 = xgpA[G];
    float xB0 = xgpB[0], xB1 = xgpB[G];

    int cur = 0;
    float h = 0.0f, hprev = 0.0f;
    const bool is_t = (s == 0);   // lane0's B-gate is cbar -> tanh

    for (int t = 0; t < TC; ++t, cur ^= 1) {
        // (1) t+2 prefetch: waited at USE two steps from now
        const int tp = (t + 2 < TC) ? (t + 2) : (TC - 1);
        const float xA2 = xgpA[(size_t)tp * G];
        const float xB2 = xgpB[(size_t)tp * G];

        // (2) deferred global store of last step's h (never waited at barrier)
        if (!LAST) {
            if (act_th && s == 0 && t > 0)
                xout[((size_t)b * TC + (t - 1)) * U + u] = hprev;
        }

        // (3) partial dots over this lane's k-slice, ALL 4 gates
        float a0 = 0.0f, a1 = 0.0f, a2 = 0.0f, a3 = 0.0f;
        const _Float16* hs = s_h + cur * HS + s * S;
#pragma unroll
        for (int kk = 0; kk < S; kk += 4) {
            f16x4 v = *(const f16x4*)(hs + kk);
            f16x2 lo = __builtin_shufflevector(v, v, 0, 1);
            f16x2 hi = __builtin_shufflevector(v, v, 2, 3);
            const int p = kk >> 1;
            a0 = fdot2_(lo, w[0][p],     a0);
            a0 = fdot2_(hi, w[0][p + 1], a0);
            a1 = fdot2_(lo, w[1][p],     a1);
            a1 = fdot2_(hi, w[1][p + 1], a1);
            a2 = fdot2_(lo, w[2][p],     a2);
            a2 = fdot2_(hi, w[2][p + 1], a2);
            a3 = fdot2_(lo, w[3][p],     a3);
            a3 = fdot2_(hi, w[3][p + 1], a3);
        }

        // (4) pair butterfly: completes all 4 gate sums in both lanes
        a0 = dpp_add<0xB1>(a0);
        a1 = dpp_add<0xB1>(a1);
        a2 = dpp_add<0xB1>(a2);
        a3 = dpp_add<0xB1>(a3);

        // (5) lane finalizes gates s (A: sigmoid) and s+2 (B: tanh on lane0)
        const float gA = ((s == 0) ? a0 : a1) + xA0;
        const float gB = ((s == 0) ? a2 : a3) + xB0;
        const float rA = fast_rcp(1.0f + __expf(-gA));            // sigmoid
        const float yB = is_t ? (-2.0f * fabsf(gB)) : (-gB);
        const float rB = fast_rcp(1.0f + __expf(yB));
        const float vB = is_t ? copysignf(fmaf(2.0f, rB, -1.0f), gB) : rB;

        // (6) pair swap, replicated c/h update
        const float Asw = dpp_mov<0xB1>(rA);
        const float Bsw = dpp_mov<0xB1>(vB);
        const float fi = (s == 0) ? rA  : Asw;   // sigmoid(i)
        const float ff = (s == 0) ? Asw : rA;    // sigmoid(f)
        const float tc = (s == 0) ? vB  : Bsw;   // tanh(cbar)
        const float fo = (s == 0) ? Bsw : vB;    // sigmoid(o)
        c = fmaf(ff, c, fi * tc);
        h = fo * tanh_fast(c);

        const int nxt = cur ^ 1;
        if (act_th && s == 0) s_h[nxt * HS + u] = (_Float16)h;
        hprev = h;
        xA0 = xA1; xA1 = xA2;
        xB0 = xB1; xB1 = xB2;
        lds_barrier();   // LDS-only: global ops stay in flight
    }

    if (!LAST) {
        if (act_th && s == 0)
            xout[((size_t)b * TC + (TC - 1)) * U + u] = hprev;
    }
    if (act_th && s == 0) {
        c_state[b * U + u] = c;
        h_state[b * U + u] = h;
    }
    if (LAST && tid == 0) {
        float acc = bout[0];
#pragma unroll
        for (int k = 0; k < U; ++k)
            acc = fmaf((float)s_h[cur * HS + k], Wout[k], acc);
        dout[b] = acc;
    }
}

#define REC_ARGS const float* __restrict__ xg, const float* __restrict__ Wh,        \
                 float* __restrict__ xout, float* __restrict__ c_state,             \
                 float* __restrict__ h_state, int first,                            \
                 const float* __restrict__ Wout, const float* __restrict__ bout,    \
                 float* __restrict__ dout
#define REC_PASS xg, Wh, xout, c_state, h_state, first, Wout, bout, dout

// 4 waves (1/SIMD), waves_per_eu(1,1): full arch-VGPR budget, no parking.
__attribute__((amdgpu_flat_work_group_size(256, 256), amdgpu_waves_per_eu(1, 1)))
__global__ void rec_l0(REC_ARGS) {
    __shared__ __align__(16) _Float16 s_h[2 * 104];   // U=100, S=52
    rec2_body<100, 52, 256, false>(s_h, REC_PASS);
}

__attribute__((amdgpu_flat_work_group_size(192, 192), amdgpu_waves_per_eu(1, 1)))
__global__ void rec_l1(REC_ARGS) {
    __shared__ __align__(16) _Float16 s_h[2 * 80];    // U=80, S=40
    rec2_body<80, 40, 192, false>(s_h, REC_PASS);
}

__attribute__((amdgpu_flat_work_group_size(128, 128), amdgpu_waves_per_eu(1, 1)))
__global__ void rec_l2(REC_ARGS) {
    __shared__ __align__(16) _Float16 s_h[2 * 56];    // U=50, S=28
    rec2_body<50, 28, 128, false>(s_h, REC_PASS);
}

__attribute__((amdgpu_flat_work_group_size(64, 64), amdgpu_waves_per_eu(1, 1)))
__global__ void rec_l3(REC_ARGS) {
    __shared__ __align__(16) _Float16 s_h[2 * 32];    // U=30, S=16
    rec2_body<30, 16, 64, true>(s_h, REC_PASS);
}

extern "C" void kernel_launch(void* const* d_in, const int* in_sizes, int n_in,
                              void* d_out, int out_size, void* d_ws, size_t ws_size,
                              hipStream_t stream)
{
    const float* seq  = (const float*)d_in[0];
    const float* Wx0  = (const float*)d_in[1];
    const float* Wh0  = (const float*)d_in[2];
    const float* b0   = (const float*)d_in[3];
    const float* Wx1  = (const float*)d_in[4];
    const float* Wh1  = (const float*)d_in[5];
    const float* b1   = (const float*)d_in[6];
    const float* Wx2  = (const float*)d_in[7];
    const float* Wh2  = (const float*)d_in[8];
    const float* b2   = (const float*)d_in[9];
    const float* Wx3  = (const float*)d_in[10];
    const float* Wh3  = (const float*)d_in[11];
    const float* b3   = (const float*)d_in[12];
    const float* Wout = (const float*)d_in[13];
    const float* bout = (const float*)d_in[14];
    float* out = (float*)d_out;

    const size_t XG_ELEMS = (size_t)BATCH * TC * 400;
    const size_t XC_ELEMS = (size_t)BATCH * TC * 100;
    float* ws  = (float*)d_ws;
    float* XGa = ws;
    float* XGb = XGa + XG_ELEMS;
    float* Xca = XGb + XG_ELEMS;
    float* Xcb = Xca + XC_ELEMS;
    float* st  = Xcb + XC_ELEMS;
    float* c0 = st + 0 * 32768; float* h0 = st + 1 * 32768;
    float* c1 = st + 2 * 32768; float* h1 = st + 3 * 32768;
    float* c2 = st + 4 * 32768; float* h2 = st + 5 * 32768;
    float* c3 = st + 6 * 32768; float* h3 = st + 7 * 32768;

    const dim3 gB(BATCH);

    for (int j = 0; j < NCHUNK; ++j) {
        const int first = (j == 0) ? 1 : 0;

        xg_gemm<64, 400><<<dim3(7, 512), 256, 0, stream>>>(
            seq + (size_t)j * TC * 64, TFULL * 64, Wx0, b0, XGa);
        rec_l0<<<gB, 256, 0, stream>>>(
            XGa, Wh0, Xca, c0, h0, first, nullptr, nullptr, nullptr);

        xg_gemm<100, 320><<<dim3(5, 512), 256, 0, stream>>>(
            Xca, TC * 100, Wx1, b1, XGb);
        rec_l1<<<gB, 192, 0, stream>>>(
            XGb, Wh1, Xcb, c1, h1, first, nullptr, nullptr, nullptr);

        xg_gemm<80, 200><<<dim3(4, 512), 256, 0, stream>>>(
            Xcb, TC * 80, Wx2, b2, XGa);
        rec_l2<<<gB, 128, 0, stream>>>(
            XGa, Wh2, Xca, c2, h2, first, nullptr, nullptr, nullptr);

        xg_gemm<50, 120><<<dim3(2, 512), 256, 0, stream>>>(
            Xca, TC * 50, Wx3, b3, XGb);
        rec_l3<<<gB, 64, 0, stream>>>(
            XGb, Wh3, nullptr, c3, h3, first, Wout, bout, out);
    }
}